// Round 7
// baseline (614.910 us; speedup 1.0000x reference)
//
#include <hip/hip_runtime.h>
#include <hip/hip_bf16.h>
#include <cstdint>
#include <cstddef>

// ---- problem constants ----
#define B_   2
#define S_   4096
#define HIDN 2048
#define H_   16
#define D_   128
#define NB_  64
#define MTOT 8192              // B_*S_
#define QKVN 6144              // merged QKV row stride
#define SCALE_ 0.08838834764831845f   // 128^-0.5

typedef unsigned short ushort_t;
typedef __attribute__((ext_vector_type(8))) short short8;
typedef __attribute__((ext_vector_type(8))) ushort_t ushort8;
typedef __attribute__((ext_vector_type(4))) float f32x4;

__device__ inline float b2f(ushort_t x){ union{unsigned u; float f;} v; v.u=((unsigned)x)<<16; return v.f; }
__device__ inline ushort_t f2b(float f){ union{unsigned u; float f;} v; v.f=f; unsigned r=(v.u + 0x7FFF + ((v.u>>16)&1))>>16; return (ushort_t)r; }

#define MFMA_BF16(a,b,c) __builtin_amdgcn_mfma_f32_16x16x32_bf16((a),(b),(c),0,0,0)

// async global->LDS, 16B per lane. LDS dest = wave-uniform base + lane*16.
__device__ inline void async16(const ushort_t* g, ushort_t* l){
  __builtin_amdgcn_global_load_lds(
      (const __attribute__((address_space(1))) void*)g,
      (__attribute__((address_space(3))) void*)l, 16, 0, 0);
}

// ------- fused fp32->bf16 convert + router partial column sums ----------
__global__ void bsa_convpart(const float* __restrict__ hs, ushort_t* __restrict__ hsB,
                             float* __restrict__ part){
  int t = threadIdx.x;
  int c  = blockIdx.x*512 + t*2;
  int sc = blockIdx.y;
  int b  = blockIdx.z;
  const float* p = hs  + ((size_t)b*S_ + (size_t)sc*128)*HIDN + c;
  ushort_t*    q = hsB + ((size_t)b*S_ + (size_t)sc*128)*HIDN + c;
  float s0=0.f, s1=0.f;
  #pragma unroll 8
  for (int i=0;i<128;i++){
    float2 v = *(const float2*)(p + (size_t)i*HIDN);
    s0 += v.x; s1 += v.y;
    unsigned pk = (unsigned)f2b(v.x) | ((unsigned)f2b(v.y)<<16);
    *(unsigned*)(q + (size_t)i*HIDN) = pk;
  }
  part[((b*32+sc)*HIDN)+c]   = s0;
  part[((b*32+sc)*HIDN)+c+1] = s1;
}

// ---------------- router stage 2, single block 1024 threads ----------------
// cm reduction: per-column j-ascending order identical to original -> bit-exact.
__global__ void bsa_router(const float* __restrict__ part, const float* __restrict__ Wr,
                           const float* __restrict__ br, int* __restrict__ counts){
  __shared__ float cm[2*HIDN];
  __shared__ float sig[2*H_];
  int t = threadIdx.x;                  // 0..1023
  {
    int b  = t>>9;                      // 0..1
    int c4 = (t&511)*4;                 // 0..2044
    float sx=0.f, sy=0.f, sz=0.f, sw=0.f;
    for (int j=0;j<32;j++){
      float4 v = *(const float4*)&part[((b*32+j)*HIDN)+c4];
      sx+=v.x; sy+=v.y; sz+=v.z; sw+=v.w;
    }
    cm[b*HIDN+c4+0]=sx*(1.0f/S_);
    cm[b*HIDN+c4+1]=sy*(1.0f/S_);
    cm[b*HIDN+c4+2]=sz*(1.0f/S_);
    cm[b*HIDN+c4+3]=sw*(1.0f/S_);
  }
  __syncthreads();
  if (t < 256){
    int g = t>>3;        // 0..31 = b*16+h
    int sl = t&7;
    int b = g>>4, h = g&15;
    float acc = 0.f;
    for (int c=sl; c<HIDN; c+=8) acc += cm[b*HIDN+c]*Wr[c*H_+h];
    acc += __shfl_xor(acc, 4);
    acc += __shfl_xor(acc, 2);
    acc += __shfl_xor(acc, 1);
    if (sl==0) sig[g] = 1.f/(1.f+expf(-(acc + br[h])));
  }
  __syncthreads();
  if (t < H_){
    float score = 0.5f*(sig[t] + sig[H_+t]);
    float eff = 0.5f*(1.0f - score*0.5f);
    int ac = (int)floorf(64.f*eff);
    if (ac < 1) ac = 1;
    counts[t] = ac;
  }
}

// ------------- weight transpose+convert: fp32 [K,N] -> bf16 [N,K] -----------
// LDS stored transposed [c][r] with XOR swizzle on r; 16B ushort8 global stores.
__global__ void bsa_transpose(const float* w0, const float* w1, const float* w2, const float* w3,
                              ushort_t* o0, ushort_t* o1, ushort_t* o2, ushort_t* o3){
  const float* src; ushort_t* dst;
  switch(blockIdx.z){
    case 0: src=w0; dst=o0; break;
    case 1: src=w1; dst=o1; break;
    case 2: src=w2; dst=o2; break;
    default: src=w3; dst=o3; break;
  }
  __shared__ ushort_t tt[64*72];     // [c][r^swz], stride 72
  int t = threadIdx.x;
  int r0 = blockIdx.y*64, c0 = blockIdx.x*64;
  #pragma unroll
  for (int it=0; it<16; it++){
    int f = it*256 + t;
    int r = f>>6, c = f&63;
    tt[c*72 + (r ^ ((c&7)<<3))] = f2b(src[(size_t)(r0+r)*HIDN + (c0+c)]);
  }
  __syncthreads();
  #pragma unroll
  for (int it=0; it<2; it++){
    int f = it*256 + t;
    int cc = f>>3, rb = (f&7)<<3;
    ushort8 v = *(const ushort8*)&tt[cc*72 + (rb ^ ((cc&7)<<3))];
    *(ushort8*)&dst[(size_t)(c0+cc)*HIDN + r0 + rb] = v;
  }
}

// ===== 256x256 4-phase bf16 GEMM, consumption-ordered reads =======
// (round-6 state; measured 197 us / MfmaUtil 46 — parked)

#define SBAR asm volatile("s_barrier" ::: "memory")
#define WVM4 asm volatile("s_waitcnt vmcnt(4)" ::: "memory")
#define WVM0 asm volatile("s_waitcnt vmcnt(0)" ::: "memory")
#define PHI  __builtin_amdgcn_s_setprio(1)
#define PLO  __builtin_amdgcn_s_setprio(0)

__device__ __forceinline__ short8 lds_frag(const ushort_t* buf, int row, int kb){
  int off = ((row<<7) + kb) ^ ((row&7)<<4);
  return *(const short8*)((const char*)buf + off);
}

// one A fragment row-pair: a[mi][ks0..1]
__device__ __forceinline__ void rd_am(short8 (&a)[4][2], int mi, const ushort_t* buf,
                                      int r0, int l16, int quad){
  a[mi][0] = lds_frag(buf, r0 + mi*16 + l16, quad*16);
  a[mi][1] = lds_frag(buf, r0 + mi*16 + l16, 64 + quad*16);
}
// one B column (16 output cols): bc[ks0..1]
__device__ __forceinline__ void rd_bc(short8 (&bc)[2], const ushort_t* buf,
                                      int row, int l16, int quad){
  bc[0] = lds_frag(buf, row + l16, quad*16);
  bc[1] = lds_frag(buf, row + l16, 64 + quad*16);
}
// one output column strip: acc[mo..mo+3][no] += a * bc  (ks0 then ks1 per elem)
__device__ __forceinline__ void mmcol(f32x4 (&acc)[8][4], const short8 (&a)[4][2],
                                      const short8 (&bc)[2], int mo, int no){
  #pragma unroll
  for (int mi=0;mi<4;mi++){
    acc[mo+mi][no] = MFMA_BF16(a[mi][0], bc[0], acc[mo+mi][no]);
    acc[mo+mi][no] = MFMA_BF16(a[mi][1], bc[1], acc[mo+mi][no]);
  }
}
// stage one 128x64 half-tile: 8 waves x 2 chunks x 64 lanes x 16B.
__device__ __forceinline__ void stage_half(ushort_t* ldsHalf, const ushort_t* g,
                                           int K, int w, int roff, int coff){
  async16(g + (size_t)(w*16 + roff)*K + coff,     ldsHalf + (w*2+0)*512);
  async16(g + (size_t)(w*16 + 8 + roff)*K + coff, ldsHalf + (w*2+1)*512);
}

template<int F32OUT>
__global__ __launch_bounds__(512, 2) void bsa_gemm8(const ushort_t* __restrict__ A,
                                                    const ushort_t* __restrict__ BT,
                                                    void* __restrict__ Cv,
                                                    int M, int N, int K){
  extern __shared__ __align__(16) ushort_t sm[];
  ushort_t* A0  = sm;              // even K-tile A  (32 KB, rows 0..255)
  ushort_t* A1  = sm + 16384;      // odd  K-tile A
  ushort_t* Bb0 = sm + 32768;      // even K-tile B
  ushort_t* Bb1 = sm + 49152;      // odd  K-tile B

  int t = threadIdx.x;
  int w = t>>6, lane = t&63, quad = lane>>4, l16 = lane&15;
  int wr = w>>2, wc = w&3;                 // 2x4 wave grid

  int nbx = N>>8;
  int nwg = (M>>8)*nbx;
  int bid = blockIdx.x;
  int swz = (bid&7)*(nwg>>3) + (bid>>3);   // bijective XCD swizzle (nwg%8==0)
  int bx = swz % nbx, by = swz / nbx;
  int m0 = by<<8, n0 = bx<<8;

  const ushort_t* Ag = A  + (size_t)m0*K;
  const ushort_t* Bg = BT + (size_t)n0*K;
  int roff = lane>>3;                      // row-in-chunk 0..7
  int coff = ((lane&7) ^ roff) << 3;       // pre-swizzled col (elements)

  f32x4 acc[8][4] = {};
  short8 a[4][2], bc[4][2];

  // prologue: tile0 (A0,Bb0) + tile1 B (Bb1): 12 loads
  stage_half(A0,        Ag,                      K, w, roff, coff);
  stage_half(A0+8192,   Ag + (size_t)128*K,      K, w, roff, coff);
  stage_half(Bb0,       Bg,                      K, w, roff, coff);
  stage_half(Bb0+8192,  Bg + (size_t)128*K,      K, w, roff, coff);
  stage_half(Bb1,       Bg + 64,                 K, w, roff, coff);
  stage_half(Bb1+8192,  Bg + (size_t)128*K + 64, K, w, roff, coff);
  WVM4;    // drains A0+Bb0 (8 oldest); Bb1 (4) stays in flight
  SBAR;    // A0, Bb0 established

  int nit = K>>7;                          // 2 K-tiles (BK=64) per iteration
  #pragma unroll 1
  for (int i=0; i<nit; i++){
    bool nl = (i+1 < nit);
    int kA  = (2*i+1)<<6;                  // odd tile 2i+1 -> A1
    int kN0 = (2*i+2)<<6;                  // next even tile -> A0/Bb0
    int kN1 = (2*i+3)<<6;                  // next odd tile B -> Bb1
    // ---- P1: stage A1; reads in consumption order; cols 0..3 of m0 ----
    stage_half(A1,      Ag + kA,                 K, w, roff, coff);
    stage_half(A1+8192, Ag + (size_t)128*K + kA, K, w, roff, coff);
    rd_bc(bc[0], Bb0, wc*64,      l16, quad);
    rd_am(a, 0,  A0,  wr*128,     l16, quad);
    rd_am(a, 1,  A0,  wr*128,     l16, quad);
    rd_am(a, 2,  A0,  wr*128,     l16, quad);
    rd_am(a, 3,  A0,  wr*128,     l16, quad);
    rd_bc(bc[1], Bb0, wc*64+16,   l16, quad);
    rd_bc(bc[2], Bb0, wc*64+32,   l16, quad);
    rd_bc(bc[3], Bb0, wc*64+48,   l16, quad);
    PHI;
    mmcol(acc, a, bc[0], 0,0);
    mmcol(acc, a, bc[1], 0,1);
    mmcol(acc, a, bc[2], 0,2);
    mmcol(acc, a, bc[3], 0,3);
    PLO;
    SBAR;
    // ---- P2: stage Bb0'; rd A0m1 (b cols still live); drain Bb1+A1 ----
    if (nl){
      stage_half(Bb0,      Bg + kN0,                 K, w, roff, coff);
      stage_half(Bb0+8192, Bg + (size_t)128*K + kN0, K, w, roff, coff);
    }
    rd_am(a, 0, A0, wr*128+64, l16, quad);
    rd_am(a, 1, A0, wr*128+64, l16, quad);
    rd_am(a, 2, A0, wr*128+64, l16, quad);
    rd_am(a, 3, A0, wr*128+64, l16, quad);
    PHI;
    mmcol(acc, a, bc[0], 4,0);
    mmcol(acc, a, bc[1], 4,1);
    mmcol(acc, a, bc[2], 4,2);
    mmcol(acc, a, bc[3], 4,3);
    PLO;
    if (nl) { WVM4; } else { WVM0; }   // Bb1+A1 established at this barrier
    SBAR;
    // ---- P3: stage A0'; reads in consumption order on A1/Bb1; drain Bb0' ----
    if (nl){
      stage_half(A0,      Ag + kN0,                 K, w, roff, coff);
      stage_half(A0+8192, Ag + (size_t)128*K + kN0, K, w, roff, coff);
    }
    rd_bc(bc[0], Bb1, wc*64,      l16, quad);
    rd_am(a, 0,  A1,  wr*128,     l16, quad);
    rd_am(a, 1,  A1,  wr*128,     l16, quad);
    rd_am(a, 2,  A1,  wr*128,     l16, quad);
    rd_am(a, 3,  A1,  wr*128,     l16, quad);
    rd_bc(bc[1], Bb1, wc*64+16,   l16, quad);
    rd_bc(bc[2], Bb1, wc*64+32,   l16, quad);
    rd_bc(bc[3], Bb1, wc*64+48,   l16, quad);
    PHI;
    mmcol(acc, a, bc[0], 0,0);
    mmcol(acc, a, bc[1], 0,1);
    mmcol(acc, a, bc[2], 0,2);
    mmcol(acc, a, bc[3], 0,3);
    PLO;
    if (nl) { WVM4; }                  // Bb0' established at this barrier
    SBAR;
    // ---- P4: stage Bb1'; rd A1m1; drain A0' ----
    if (nl){
      stage_half(Bb1,      Bg + kN1,                 K, w, roff, coff);
      stage_half(Bb1+8192, Bg + (size_t)128*K + kN1, K, w, roff, coff);
    }
    rd_am(a, 0, A1, wr*128+64, l16, quad);
    rd_am(a, 1, A1, wr*128+64, l16, quad);
    rd_am(a, 2, A1, wr*128+64, l16, quad);
    rd_am(a, 3, A1, wr*128+64, l16, quad);
    PHI;
    mmcol(acc, a, bc[0], 4,0);
    mmcol(acc, a, bc[1], 4,1);
    mmcol(acc, a, bc[2], 4,2);
    mmcol(acc, a, bc[3], 4,3);
    PLO;
    if (nl) { WVM4; }                  // A0' established at this barrier
    SBAR;
  }

  // epilogue: direct C write (same lane mapping as verified kernel)
  #pragma unroll
  for (int mi=0; mi<8; mi++)
    #pragma unroll
    for (int ni=0; ni<4; ni++){
      int m = m0 + wr*128 + mi*16 + quad*4;
      int n = n0 + wc*64 + ni*16 + l16;
      #pragma unroll
      for (int r=0;r<4;r++){
        if (F32OUT) ((float*)Cv)[(size_t)(m+r)*N + n] = acc[mi][ni][r];
        else        ((ushort_t*)Cv)[(size_t)(m+r)*N + n] = f2b(acc[mi][ni][r]);
      }
    }
}

// ---------------- block-diagonal top-k attention ----------------
// Top-k selection via ballot-based MSB radix-select (NO cross-lane sort):
// the old 21-step bitonic sort was 1344 shfl (ds_swizzle) per wave on the
// per-CU-shared LDS pipe (~6cy/op, ~43K ops/CU) — the dominant attn cost.
// Radix-select uses only VALU (v_cmp ballot) + SALU (popcount/cselect):
// exact cnt-th-largest key; tie-break by lane index identical to the
// stable-argsort reference. Same m/mx/sum math order -> same output.
__global__ __launch_bounds__(256) void bsa_attn(const ushort_t* __restrict__ QKV,
                                                const int* __restrict__ counts,
                                                ushort_t* __restrict__ O){
  __shared__ __align__(16) ushort_t regA[64*136];
  __shared__ __align__(16) ushort_t regB[64*136];
  __shared__ __align__(16) ushort_t Ps[64*72];
  float* Sc = (float*)regA;

  int t = threadIdx.x, w = t>>6, lane = t&63, quad = lane>>4, l16 = lane&15;
  int bid = blockIdx.x;
  int b  = bid>>10;
  int h  = (bid>>6)&15;
  int nb = bid&63;
  size_t qbase = ((size_t)b*S_ + (size_t)nb*64)*QKVN + (size_t)h*D_;
  size_t obase = ((size_t)b*S_ + (size_t)nb*64)*HIDN + (size_t)h*D_;

  int4 vre[4];
  #pragma unroll
  for (int it=0; it<4; it++){
    int f = it*256 + t;
    int r = f>>4, c = (f&15)*8;
    vre[it] = *(const int4*)(QKV + qbase + 4096 + (size_t)r*QKVN + c);
  }

  #pragma unroll
  for (int it=0; it<4; it++){
    int f = it*256 + t;
    int r = f>>4, c = (f&15)*8;
    *(int4*)(&regA[r*136+c]) = *(const int4*)(QKV + qbase +        (size_t)r*QKVN + c);
    *(int4*)(&regB[r*136+c]) = *(const int4*)(QKV + qbase + 2048 + (size_t)r*QKVN + c);
  }
  __syncthreads();

  f32x4 sacc[4] = {};
  #pragma unroll
  for (int ks=0; ks<4; ks++){
    short8 afr = *(const short8*)(&regA[(w*16 + l16)*136 + ks*32 + quad*8]);
    #pragma unroll
    for (int nt=0; nt<4; nt++){
      short8 bfr = *(const short8*)(&regB[(nt*16 + l16)*136 + ks*32 + quad*8]);
      sacc[nt] = MFMA_BF16(afr, bfr, sacc[nt]);
    }
  }
  __syncthreads();

  #pragma unroll
  for (int nt=0; nt<4; nt++)
    #pragma unroll
    for (int r=0;r<4;r++)
      Sc[(w*16 + quad*4 + r)*68 + nt*16 + l16] = sacc[nt][r]*SCALE_;
  #pragma unroll
  for (int it=0; it<4; it++){
    int f = it*256 + t;
    int r = f>>4, c = (f&15)*8;
    *(int4*)(&regB[r*136+c]) = vre[it];
  }

  int cnt = counts[h];
  for (int g=0; g<4; g++){
    float s[4]; unsigned key[4], pref[4]; int need[4];
    #pragma unroll
    for (int rr=0; rr<4; rr++){
      s[rr] = Sc[(w*16 + g*4 + rr)*68 + lane];
      unsigned u = __float_as_uint(s[rr]);
      key[rr] = u ^ ((unsigned)((int)u >> 31) | 0x80000000u);  // orderable key
      pref[rr] = 0u; need[rr] = cnt;
    }
    // MSB radix-select: after loop, pref[rr] = cnt-th largest key of the row.
    // candidate-with-bit-1 <=> (key^pref)>>bit == 1 (higher bits match, bit set).
    #pragma unroll
    for (int bit=31; bit>=0; --bit){
      #pragma unroll
      for (int rr=0; rr<4; rr++){
        unsigned long long bb = __ballot(((key[rr] ^ pref[rr]) >> bit) == 1u);
        int c = __popcll(bb);
        bool takebit = (c >= need[rr]);      // wave-uniform
        pref[rr] |= takebit ? (1u<<bit) : 0u;
        need[rr] -= takebit ? 0 : c;
      }
    }
    #pragma unroll
    for (int rr=0; rr<4; rr++){
      unsigned long long bgt = __ballot(key[rr] > pref[rr]);
      unsigned long long beq = __ballot(key[rr] == pref[rr]);
      int G = __popcll(bgt);
      int eqr = __popcll(beq & ((1ull<<lane)-1ull));
      bool keep = (key[rr] > pref[rr]) || ((key[rr] == pref[rr]) && (eqr < cnt - G));
      float m = keep ? s[rr] : 0.0f;         // dropped -> 0.0 (not -inf)
      float vmax = s[rr];
      #pragma unroll
      for (int off=32; off; off>>=1) vmax = fmaxf(vmax, __shfl_xor(vmax, off));
      float mx = fmaxf(vmax, 0.0f);          // max kept = global max; zeros present
      float e = __expf(m - mx);
      float sum = e;
      #pragma unroll
      for (int off=32; off; off>>=1) sum += __shfl_xor(sum, off);
      Ps[(w*16 + g*4 + rr)*72 + lane] = f2b(e/sum);
    }
  }
  __syncthreads();

  f32x4 oacc[4][2] = {};
  #pragma unroll
  for (int ks=0; ks<2; ks++){
    short8 bv[2];
    #pragma unroll
    for (int jj=0; jj<2; jj++){
      int n = (w*2+jj)*16 + l16;
      short8 x;
      #pragma unroll
      for (int j=0;j<8;j++){
        int k = ks*32 + quad*8 + j;
        x[j] = (short)regB[k*136 + n];
      }
      bv[jj] = x;
    }
    #pragma unroll
    for (int mt=0; mt<4; mt++){
      short8 aP = *(const short8*)(&Ps[(mt*16 + l16)*72 + ks*32 + quad*8]);
      #pragma unroll
      for (int jj=0; jj<2; jj++)
        oacc[mt][jj] = MFMA_BF16(aP, bv[jj], oacc[mt][jj]);
    }
  }
  #pragma unroll
  for (int mt=0; mt<4; mt++)
    #pragma unroll
    for (int jj=0; jj<2; jj++){
      int row = mt*16 + quad*4;
      int col = (w*2+jj)*16 + l16;
      #pragma unroll
      for (int r=0;r<4;r++)
        O[obase + (size_t)(row+r)*HIDN + col] = f2b(oacc[mt][jj][r]);
    }
}

// ---------------- launch ----------------
extern "C" void kernel_launch(void* const* d_in, const int* in_sizes, int n_in,
                              void* d_out, int out_size, void* d_ws, size_t ws_size,
                              hipStream_t stream) {
  const float* hs = (const float*)d_in[0];
  const float* Wq = (const float*)d_in[1];
  const float* Wk = (const float*)d_in[2];
  const float* Wv = (const float*)d_in[3];
  const float* Wo = (const float*)d_in[4];
  const float* Wr = (const float*)d_in[5];
  const float* br = (const float*)d_in[6];
  float* out = (float*)d_out;
  char* ws = (char*)d_ws;

  const size_t MB = 1024u*1024u;
  float*    part   = (float*)(ws + 0);                 // 512 KB
  int*      counts = (int*)(ws + 512u*1024u);          // 64 B
  ushort_t* hsB    = (ushort_t*)(ws + 1*MB);           // 32 MB bf16 hidden
  ushort_t* WqT    = (ushort_t*)(ws + 33*MB);          // 8 MB each; q|k|v contiguous
  ushort_t* WkT    = (ushort_t*)(ws + 41*MB);
  ushort_t* WvT    = (ushort_t*)(ws + 49*MB);
  ushort_t* WoT    = (ushort_t*)(ws + 57*MB);
  ushort_t* QKV    = (ushort_t*)(ws + 65*MB);          // 96 MB: [8192][6144]
  ushort_t* AO     = hsB;   // alias: hsB dead after the QKV GEMM

  static bool attr_done = false;
  if (!attr_done){
    hipFuncSetAttribute((const void*)&bsa_gemm8<0>,
                        hipFuncAttributeMaxDynamicSharedMemorySize, 131072);
    hipFuncSetAttribute((const void*)&bsa_gemm8<1>,
                        hipFuncAttributeMaxDynamicSharedMemorySize, 131072);
    attr_done = true;
  }

  bsa_convpart  <<<dim3(4,32,2),  256, 0, stream>>>(hs, hsB, part);
  bsa_router    <<<1,            1024, 0, stream>>>(part, Wr, br, counts);
  bsa_transpose <<<dim3(32,32,4), 256, 0, stream>>>(Wq,Wk,Wv,Wo, WqT,WkT,WvT,WoT);
  // merged QKV projection: 32x24 = 768 blocks of 256^2
  bsa_gemm8<0><<<dim3(768), 512, 131072, stream>>>(hsB, WqT, (void*)QKV, MTOT, QKVN, 2048);
  bsa_attn      <<<2048,          256, 0, stream>>>(QKV, counts, AO);
  // Wo projection: 32x8 = 256 blocks
  bsa_gemm8<1><<<dim3(256), 512, 131072, stream>>>(AO, WoT, (void*)out, MTOT, 2048, 2048);
}

// Round 8
// 590.729 us; speedup vs baseline: 1.0409x; 1.0409x over previous
//
#include <hip/hip_runtime.h>
#include <hip/hip_bf16.h>
#include <cstdint>
#include <cstddef>

// ---- problem constants ----
#define B_   2
#define S_   4096
#define HIDN 2048
#define H_   16
#define D_   128
#define NB_  64
#define MTOT 8192              // B_*S_
#define QKVN 6144              // merged QKV row stride
#define SCALE_ 0.08838834764831845f   // 128^-0.5

typedef unsigned short ushort_t;
typedef __attribute__((ext_vector_type(8))) short short8;
typedef __attribute__((ext_vector_type(8))) ushort_t ushort8;
typedef __attribute__((ext_vector_type(4))) float f32x4;
typedef __attribute__((ext_vector_type(4))) unsigned uint4v;

__device__ inline float b2f(ushort_t x){ union{unsigned u; float f;} v; v.u=((unsigned)x)<<16; return v.f; }
__device__ inline ushort_t f2b(float f){ union{unsigned u; float f;} v; v.f=f; unsigned r=(v.u + 0x7FFF + ((v.u>>16)&1))>>16; return (ushort_t)r; }

#define MFMA_BF16(a,b,c) __builtin_amdgcn_mfma_f32_16x16x32_bf16((a),(b),(c),0,0,0)

// async global->LDS, 16B per lane. LDS dest = wave-uniform base + lane*16.
__device__ inline void async16(const ushort_t* g, ushort_t* l){
  __builtin_amdgcn_global_load_lds(
      (const __attribute__((address_space(1))) void*)g,
      (__attribute__((address_space(3))) void*)l, 16, 0, 0);
}

// ------- fused fp32->bf16 convert + router partial column sums ----------
__global__ void bsa_convpart(const float* __restrict__ hs, ushort_t* __restrict__ hsB,
                             float* __restrict__ part){
  int t = threadIdx.x;
  int c  = blockIdx.x*512 + t*2;
  int sc = blockIdx.y;
  int b  = blockIdx.z;
  const float* p = hs  + ((size_t)b*S_ + (size_t)sc*128)*HIDN + c;
  ushort_t*    q = hsB + ((size_t)b*S_ + (size_t)sc*128)*HIDN + c;
  float s0=0.f, s1=0.f;
  #pragma unroll 8
  for (int i=0;i<128;i++){
    float2 v = *(const float2*)(p + (size_t)i*HIDN);
    s0 += v.x; s1 += v.y;
    unsigned pk = (unsigned)f2b(v.x) | ((unsigned)f2b(v.y)<<16);
    *(unsigned*)(q + (size_t)i*HIDN) = pk;
  }
  part[((b*32+sc)*HIDN)+c]   = s0;
  part[((b*32+sc)*HIDN)+c+1] = s1;
}

// ------ router stage 1: parallel column means (4 blocks x 256 threads) ------
// Per-column j-ascending add order identical to the old single-block version
// -> bit-exact cm values. Old single-block reduce idled 255 CUs for ~15-20us.
__global__ void bsa_router1(const float* __restrict__ part, float* __restrict__ cm){
  int g = blockIdx.x*256 + threadIdx.x;   // 0..1023
  int b  = g>>9;                          // 0..1
  int c4 = (g&511)*4;                     // 0..2044
  float sx=0.f, sy=0.f, sz=0.f, sw=0.f;
  for (int j=0;j<32;j++){
    float4 v = *(const float4*)&part[((b*32+j)*HIDN)+c4];
    sx+=v.x; sy+=v.y; sz+=v.z; sw+=v.w;
  }
  cm[b*HIDN+c4+0]=sx*(1.0f/S_);
  cm[b*HIDN+c4+1]=sy*(1.0f/S_);
  cm[b*HIDN+c4+2]=sz*(1.0f/S_);
  cm[b*HIDN+c4+3]=sw*(1.0f/S_);
}

// ------ router stage 2: tiny single block (16KB read, ~3us) ------
__global__ void bsa_router2(const float* __restrict__ cm, const float* __restrict__ Wr,
                            const float* __restrict__ br, int* __restrict__ counts){
  __shared__ float sig[2*H_];
  int t = threadIdx.x;                 // 0..255
  {
    int g = t>>3;        // 0..31 = b*16+h
    int sl = t&7;
    int b = g>>4, h = g&15;
    float acc = 0.f;
    for (int c=sl; c<HIDN; c+=8) acc += cm[b*HIDN+c]*Wr[c*H_+h];
    acc += __shfl_xor(acc, 4);
    acc += __shfl_xor(acc, 2);
    acc += __shfl_xor(acc, 1);
    if (sl==0) sig[g] = 1.f/(1.f+expf(-(acc + br[h])));
  }
  __syncthreads();
  if (t < H_){
    float score = 0.5f*(sig[t] + sig[H_+t]);
    float eff = 0.5f*(1.0f - score*0.5f);
    int ac = (int)floorf(64.f*eff);
    if (ac < 1) ac = 1;
    counts[t] = ac;
  }
}

// ------------- weight transpose+convert: fp32 [K,N] -> bf16 [N,K] -----------
// Conflict-free LDS: row-pairs packed as u32, tile u32[64][33] (pad 33).
// Write bank = (c + r2) % 32 -> all 32 banks across a wave (2-way, free);
// uint4 reads ~2-way. (The old [c][r^swz] stride-72 layout was 8-way
// conflicted BOTH directions: bank = (lane*36+..)%32 -> lanes 8 apart collide.)
__global__ void bsa_transpose(const float* w0, const float* w1, const float* w2, const float* w3,
                              ushort_t* o0, ushort_t* o1, ushort_t* o2, ushort_t* o3){
  const float* src; ushort_t* dst;
  switch(blockIdx.z){
    case 0: src=w0; dst=o0; break;
    case 1: src=w1; dst=o1; break;
    case 2: src=w2; dst=o2; break;
    default: src=w3; dst=o3; break;
  }
  __shared__ unsigned tt[64*33];     // [c][r2] u32 = rows (2r2, 2r2+1) packed
  int t = threadIdx.x;
  int r0 = blockIdx.y*64, c0 = blockIdx.x*64;
  #pragma unroll
  for (int it=0; it<8; it++){
    int f = it*256 + t;              // 0..2047
    int r2 = f>>6;                   // 0..31 (wave-constant)
    int c  = f&63;                   // lane
    float x0 = src[(size_t)(r0+2*r2  )*HIDN + (c0+c)];
    float x1 = src[(size_t)(r0+2*r2+1)*HIDN + (c0+c)];
    tt[c*33 + r2] = (unsigned)f2b(x0) | ((unsigned)f2b(x1)<<16);
  }
  __syncthreads();
  #pragma unroll
  for (int it=0; it<2; it++){
    int f = it*256 + t;              // 0..511
    int cc = f>>3, k = f&7;          // row cc, 8-ushort chunk k
    uint4v v = *(const uint4v*)&tt[cc*33 + k*4];
    *(uint4v*)&dst[(size_t)(c0+cc)*HIDN + r0 + k*8] = v;
  }
}

// ===== 256x256 4-phase bf16 GEMM, consumption-ordered reads =======
// (round-6 state; measured 197 us / MfmaUtil 46 — parked)

#define SBAR asm volatile("s_barrier" ::: "memory")
#define WVM4 asm volatile("s_waitcnt vmcnt(4)" ::: "memory")
#define WVM0 asm volatile("s_waitcnt vmcnt(0)" ::: "memory")
#define PHI  __builtin_amdgcn_s_setprio(1)
#define PLO  __builtin_amdgcn_s_setprio(0)

__device__ __forceinline__ short8 lds_frag(const ushort_t* buf, int row, int kb){
  int off = ((row<<7) + kb) ^ ((row&7)<<4);
  return *(const short8*)((const char*)buf + off);
}

// one A fragment row-pair: a[mi][ks0..1]
__device__ __forceinline__ void rd_am(short8 (&a)[4][2], int mi, const ushort_t* buf,
                                      int r0, int l16, int quad){
  a[mi][0] = lds_frag(buf, r0 + mi*16 + l16, quad*16);
  a[mi][1] = lds_frag(buf, r0 + mi*16 + l16, 64 + quad*16);
}
// one B column (16 output cols): bc[ks0..1]
__device__ __forceinline__ void rd_bc(short8 (&bc)[2], const ushort_t* buf,
                                      int row, int l16, int quad){
  bc[0] = lds_frag(buf, row + l16, quad*16);
  bc[1] = lds_frag(buf, row + l16, 64 + quad*16);
}
// one output column strip: acc[mo..mo+3][no] += a * bc  (ks0 then ks1 per elem)
__device__ __forceinline__ void mmcol(f32x4 (&acc)[8][4], const short8 (&a)[4][2],
                                      const short8 (&bc)[2], int mo, int no){
  #pragma unroll
  for (int mi=0;mi<4;mi++){
    acc[mo+mi][no] = MFMA_BF16(a[mi][0], bc[0], acc[mo+mi][no]);
    acc[mo+mi][no] = MFMA_BF16(a[mi][1], bc[1], acc[mo+mi][no]);
  }
}
// stage one 128x64 half-tile: 8 waves x 2 chunks x 64 lanes x 16B.
__device__ __forceinline__ void stage_half(ushort_t* ldsHalf, const ushort_t* g,
                                           int K, int w, int roff, int coff){
  async16(g + (size_t)(w*16 + roff)*K + coff,     ldsHalf + (w*2+0)*512);
  async16(g + (size_t)(w*16 + 8 + roff)*K + coff, ldsHalf + (w*2+1)*512);
}

template<int F32OUT>
__global__ __launch_bounds__(512, 2) void bsa_gemm8(const ushort_t* __restrict__ A,
                                                    const ushort_t* __restrict__ BT,
                                                    void* __restrict__ Cv,
                                                    int M, int N, int K){
  extern __shared__ __align__(16) ushort_t sm[];
  ushort_t* A0  = sm;              // even K-tile A  (32 KB, rows 0..255)
  ushort_t* A1  = sm + 16384;      // odd  K-tile A
  ushort_t* Bb0 = sm + 32768;      // even K-tile B
  ushort_t* Bb1 = sm + 49152;      // odd  K-tile B

  int t = threadIdx.x;
  int w = t>>6, lane = t&63, quad = lane>>4, l16 = lane&15;
  int wr = w>>2, wc = w&3;                 // 2x4 wave grid

  int nbx = N>>8;
  int nwg = (M>>8)*nbx;
  int bid = blockIdx.x;
  int swz = (bid&7)*(nwg>>3) + (bid>>3);   // bijective XCD swizzle (nwg%8==0)
  int bx = swz % nbx, by = swz / nbx;
  int m0 = by<<8, n0 = bx<<8;

  const ushort_t* Ag = A  + (size_t)m0*K;
  const ushort_t* Bg = BT + (size_t)n0*K;
  int roff = lane>>3;                      // row-in-chunk 0..7
  int coff = ((lane&7) ^ roff) << 3;       // pre-swizzled col (elements)

  f32x4 acc[8][4] = {};
  short8 a[4][2], bc[4][2];

  // prologue: tile0 (A0,Bb0) + tile1 B (Bb1): 12 loads
  stage_half(A0,        Ag,                      K, w, roff, coff);
  stage_half(A0+8192,   Ag + (size_t)128*K,      K, w, roff, coff);
  stage_half(Bb0,       Bg,                      K, w, roff, coff);
  stage_half(Bb0+8192,  Bg + (size_t)128*K,      K, w, roff, coff);
  stage_half(Bb1,       Bg + 64,                 K, w, roff, coff);
  stage_half(Bb1+8192,  Bg + (size_t)128*K + 64, K, w, roff, coff);
  WVM4;    // drains A0+Bb0 (8 oldest); Bb1 (4) stays in flight
  SBAR;    // A0, Bb0 established

  int nit = K>>7;                          // 2 K-tiles (BK=64) per iteration
  #pragma unroll 1
  for (int i=0; i<nit; i++){
    bool nl = (i+1 < nit);
    int kA  = (2*i+1)<<6;                  // odd tile 2i+1 -> A1
    int kN0 = (2*i+2)<<6;                  // next even tile -> A0/Bb0
    int kN1 = (2*i+3)<<6;                  // next odd tile B -> Bb1
    // ---- P1: stage A1; reads in consumption order; cols 0..3 of m0 ----
    stage_half(A1,      Ag + kA,                 K, w, roff, coff);
    stage_half(A1+8192, Ag + (size_t)128*K + kA, K, w, roff, coff);
    rd_bc(bc[0], Bb0, wc*64,      l16, quad);
    rd_am(a, 0,  A0,  wr*128,     l16, quad);
    rd_am(a, 1,  A0,  wr*128,     l16, quad);
    rd_am(a, 2,  A0,  wr*128,     l16, quad);
    rd_am(a, 3,  A0,  wr*128,     l16, quad);
    rd_bc(bc[1], Bb0, wc*64+16,   l16, quad);
    rd_bc(bc[2], Bb0, wc*64+32,   l16, quad);
    rd_bc(bc[3], Bb0, wc*64+48,   l16, quad);
    PHI;
    mmcol(acc, a, bc[0], 0,0);
    mmcol(acc, a, bc[1], 0,1);
    mmcol(acc, a, bc[2], 0,2);
    mmcol(acc, a, bc[3], 0,3);
    PLO;
    SBAR;
    // ---- P2: stage Bb0'; rd A0m1 (b cols still live); drain Bb1+A1 ----
    if (nl){
      stage_half(Bb0,      Bg + kN0,                 K, w, roff, coff);
      stage_half(Bb0+8192, Bg + (size_t)128*K + kN0, K, w, roff, coff);
    }
    rd_am(a, 0, A0, wr*128+64, l16, quad);
    rd_am(a, 1, A0, wr*128+64, l16, quad);
    rd_am(a, 2, A0, wr*128+64, l16, quad);
    rd_am(a, 3, A0, wr*128+64, l16, quad);
    PHI;
    mmcol(acc, a, bc[0], 4,0);
    mmcol(acc, a, bc[1], 4,1);
    mmcol(acc, a, bc[2], 4,2);
    mmcol(acc, a, bc[3], 4,3);
    PLO;
    if (nl) { WVM4; } else { WVM0; }   // Bb1+A1 established at this barrier
    SBAR;
    // ---- P3: stage A0'; reads in consumption order on A1/Bb1; drain Bb0' ----
    if (nl){
      stage_half(A0,      Ag + kN0,                 K, w, roff, coff);
      stage_half(A0+8192, Ag + (size_t)128*K + kN0, K, w, roff, coff);
    }
    rd_bc(bc[0], Bb1, wc*64,      l16, quad);
    rd_am(a, 0,  A1,  wr*128,     l16, quad);
    rd_am(a, 1,  A1,  wr*128,     l16, quad);
    rd_am(a, 2,  A1,  wr*128,     l16, quad);
    rd_am(a, 3,  A1,  wr*128,     l16, quad);
    rd_bc(bc[1], Bb1, wc*64+16,   l16, quad);
    rd_bc(bc[2], Bb1, wc*64+32,   l16, quad);
    rd_bc(bc[3], Bb1, wc*64+48,   l16, quad);
    PHI;
    mmcol(acc, a, bc[0], 0,0);
    mmcol(acc, a, bc[1], 0,1);
    mmcol(acc, a, bc[2], 0,2);
    mmcol(acc, a, bc[3], 0,3);
    PLO;
    if (nl) { WVM4; }                  // Bb0' established at this barrier
    SBAR;
    // ---- P4: stage Bb1'; rd A1m1; drain A0' ----
    if (nl){
      stage_half(Bb1,      Bg + kN1,                 K, w, roff, coff);
      stage_half(Bb1+8192, Bg + (size_t)128*K + kN1, K, w, roff, coff);
    }
    rd_am(a, 0, A1, wr*128+64, l16, quad);
    rd_am(a, 1, A1, wr*128+64, l16, quad);
    rd_am(a, 2, A1, wr*128+64, l16, quad);
    rd_am(a, 3, A1, wr*128+64, l16, quad);
    PHI;
    mmcol(acc, a, bc[0], 4,0);
    mmcol(acc, a, bc[1], 4,1);
    mmcol(acc, a, bc[2], 4,2);
    mmcol(acc, a, bc[3], 4,3);
    PLO;
    if (nl) { WVM4; }                  // A0' established at this barrier
    SBAR;
  }

  // epilogue: direct C write (same lane mapping as verified kernel)
  #pragma unroll
  for (int mi=0; mi<8; mi++)
    #pragma unroll
    for (int ni=0; ni<4; ni++){
      int m = m0 + wr*128 + mi*16 + quad*4;
      int n = n0 + wc*64 + ni*16 + l16;
      #pragma unroll
      for (int r=0;r<4;r++){
        if (F32OUT) ((float*)Cv)[(size_t)(m+r)*N + n] = acc[mi][ni][r];
        else        ((ushort_t*)Cv)[(size_t)(m+r)*N + n] = f2b(acc[mi][ni][r]);
      }
    }
}

// ---------------- block-diagonal top-k attention (r6 bitonic — best) --------
__global__ __launch_bounds__(256) void bsa_attn(const ushort_t* __restrict__ QKV,
                                                const int* __restrict__ counts,
                                                ushort_t* __restrict__ O){
  __shared__ __align__(16) ushort_t regA[64*136];
  __shared__ __align__(16) ushort_t regB[64*136];
  __shared__ __align__(16) ushort_t Ps[64*72];
  float* Sc = (float*)regA;

  int t = threadIdx.x, w = t>>6, lane = t&63, quad = lane>>4, l16 = lane&15;
  int bid = blockIdx.x;
  int b  = bid>>10;
  int h  = (bid>>6)&15;
  int nb = bid&63;
  size_t qbase = ((size_t)b*S_ + (size_t)nb*64)*QKVN + (size_t)h*D_;
  size_t obase = ((size_t)b*S_ + (size_t)nb*64)*HIDN + (size_t)h*D_;

  int4 vre[4];
  #pragma unroll
  for (int it=0; it<4; it++){
    int f = it*256 + t;
    int r = f>>4, c = (f&15)*8;
    vre[it] = *(const int4*)(QKV + qbase + 4096 + (size_t)r*QKVN + c);
  }

  #pragma unroll
  for (int it=0; it<4; it++){
    int f = it*256 + t;
    int r = f>>4, c = (f&15)*8;
    *(int4*)(&regA[r*136+c]) = *(const int4*)(QKV + qbase +        (size_t)r*QKVN + c);
    *(int4*)(&regB[r*136+c]) = *(const int4*)(QKV + qbase + 2048 + (size_t)r*QKVN + c);
  }
  __syncthreads();

  f32x4 sacc[4] = {};
  #pragma unroll
  for (int ks=0; ks<4; ks++){
    short8 afr = *(const short8*)(&regA[(w*16 + l16)*136 + ks*32 + quad*8]);
    #pragma unroll
    for (int nt=0; nt<4; nt++){
      short8 bfr = *(const short8*)(&regB[(nt*16 + l16)*136 + ks*32 + quad*8]);
      sacc[nt] = MFMA_BF16(afr, bfr, sacc[nt]);
    }
  }
  __syncthreads();

  #pragma unroll
  for (int nt=0; nt<4; nt++)
    #pragma unroll
    for (int r=0;r<4;r++)
      Sc[(w*16 + quad*4 + r)*68 + nt*16 + l16] = sacc[nt][r]*SCALE_;
  #pragma unroll
  for (int it=0; it<4; it++){
    int f = it*256 + t;
    int r = f>>4, c = (f&15)*8;
    *(int4*)(&regB[r*136+c]) = vre[it];
  }

  int cnt = counts[h];
  for (int g=0; g<4; g++){
    float s[4], v[4];
    #pragma unroll
    for (int rr=0; rr<4; rr++){
      s[rr] = Sc[(w*16 + g*4 + rr)*68 + lane];
      v[rr] = s[rr];
    }
    #pragma unroll
    for (int k=2; k<=64; k<<=1){
      #pragma unroll
      for (int m=k>>1; m>=1; m>>=1){
        #pragma unroll
        for (int rr=0; rr<4; rr++){
          float o = __shfl_xor(v[rr], m);
          bool keepMin = (((lane & k)==0) == ((lane & m)==0));
          float lo = fminf(v[rr], o), hi = fmaxf(v[rr], o);
          v[rr] = keepMin ? lo : hi;
        }
      }
    }
    #pragma unroll
    for (int rr=0; rr<4; rr++){
      float T = __shfl(v[rr], 64 - cnt);
      unsigned long long gt = __ballot(s[rr] > T);
      unsigned long long eq = __ballot(s[rr] == T);
      int G = __popcll(gt);
      int eqr = __popcll(eq & ((1ull<<lane)-1ull));
      bool keep = (s[rr] > T) || ((s[rr] == T) && (eqr < cnt - G));
      float m = keep ? s[rr] : 0.0f;
      float mx = fmaxf(__shfl(v[rr], 63), 0.0f);
      float e = __expf(m - mx);
      float sum = e;
      #pragma unroll
      for (int off=32; off; off>>=1) sum += __shfl_xor(sum, off);
      Ps[(w*16 + g*4 + rr)*72 + lane] = f2b(e/sum);
    }
  }
  __syncthreads();

  f32x4 oacc[4][2] = {};
  #pragma unroll
  for (int ks=0; ks<2; ks++){
    short8 bv[2];
    #pragma unroll
    for (int jj=0; jj<2; jj++){
      int n = (w*2+jj)*16 + l16;
      short8 x;
      #pragma unroll
      for (int j=0;j<8;j++){
        int k = ks*32 + quad*8 + j;
        x[j] = (short)regB[k*136 + n];
      }
      bv[jj] = x;
    }
    #pragma unroll
    for (int mt=0; mt<4; mt++){
      short8 aP = *(const short8*)(&Ps[(mt*16 + l16)*72 + ks*32 + quad*8]);
      #pragma unroll
      for (int jj=0; jj<2; jj++)
        oacc[mt][jj] = MFMA_BF16(aP, bv[jj], oacc[mt][jj]);
    }
  }
  #pragma unroll
  for (int mt=0; mt<4; mt++)
    #pragma unroll
    for (int jj=0; jj<2; jj++){
      int row = mt*16 + quad*4;
      int col = (w*2+jj)*16 + l16;
      #pragma unroll
      for (int r=0;r<4;r++)
        O[obase + (size_t)(row+r)*HIDN + col] = f2b(oacc[mt][jj][r]);
    }
}

// ---------------- launch ----------------
extern "C" void kernel_launch(void* const* d_in, const int* in_sizes, int n_in,
                              void* d_out, int out_size, void* d_ws, size_t ws_size,
                              hipStream_t stream) {
  const float* hs = (const float*)d_in[0];
  const float* Wq = (const float*)d_in[1];
  const float* Wk = (const float*)d_in[2];
  const float* Wv = (const float*)d_in[3];
  const float* Wo = (const float*)d_in[4];
  const float* Wr = (const float*)d_in[5];
  const float* br = (const float*)d_in[6];
  float* out = (float*)d_out;
  char* ws = (char*)d_ws;

  const size_t MB = 1024u*1024u;
  float*    part   = (float*)(ws + 0);                 // 512 KB
  int*      counts = (int*)(ws + 512u*1024u);          // 64 B
  float*    cm     = (float*)(ws + 768u*1024u);        // 16 KB column means
  ushort_t* hsB    = (ushort_t*)(ws + 1*MB);           // 32 MB bf16 hidden
  ushort_t* WqT    = (ushort_t*)(ws + 33*MB);          // 8 MB each; q|k|v contiguous
  ushort_t* WkT    = (ushort_t*)(ws + 41*MB);
  ushort_t* WvT    = (ushort_t*)(ws + 49*MB);
  ushort_t* WoT    = (ushort_t*)(ws + 57*MB);
  ushort_t* QKV    = (ushort_t*)(ws + 65*MB);          // 96 MB: [8192][6144]
  ushort_t* AO     = hsB;   // alias: hsB dead after the QKV GEMM

  static bool attr_done = false;
  if (!attr_done){
    hipFuncSetAttribute((const void*)&bsa_gemm8<0>,
                        hipFuncAttributeMaxDynamicSharedMemorySize, 131072);
    hipFuncSetAttribute((const void*)&bsa_gemm8<1>,
                        hipFuncAttributeMaxDynamicSharedMemorySize, 131072);
    attr_done = true;
  }

  bsa_convpart  <<<dim3(4,32,2),  256, 0, stream>>>(hs, hsB, part);
  bsa_router1   <<<4,             256, 0, stream>>>(part, cm);
  bsa_transpose <<<dim3(32,32,4), 256, 0, stream>>>(Wq,Wk,Wv,Wo, WqT,WkT,WvT,WoT);
  bsa_router2   <<<1,             256, 0, stream>>>(cm, Wr, br, counts);
  // merged QKV projection: 32x24 = 768 blocks of 256^2
  bsa_gemm8<0><<<dim3(768), 512, 131072, stream>>>(hsB, WqT, (void*)QKV, MTOT, QKVN, 2048);
  bsa_attn      <<<2048,          256, 0, stream>>>(QKV, counts, AO);
  // Wo projection: 32x8 = 256 blocks
  bsa_gemm8<1><<<dim3(256), 512, 131072, stream>>>(AO, WoT, (void*)out, MTOT, 2048, 2048);
}